// Round 1
// 186.489 us; speedup vs baseline: 1.0224x; 1.0224x over previous
//
#include <hip/hip_runtime.h>

typedef __bf16 bf16;
typedef __bf16 bf16x4 __attribute__((ext_vector_type(4)));
typedef __bf16 bf16x8 __attribute__((ext_vector_type(8)));
typedef float f32x4 __attribute__((ext_vector_type(4)));

#define S_LEN 2048
#define D_DIM 1024
#define N_HEAD 16
#define HEAD_DIM 64
#define M_TOK 4096
#define BH 32

#define EXP2F(x) __builtin_amdgcn_exp2f(x)
// 1/sqrt(64) * log2(e)
#define Q_SCALE 0.18033688f

// LDS bank swizzle: conflict-free for our b64/b128 access patterns (stride 64, no pad)
#define SW(r, c) ((c) ^ (((r) & 3) << 4))

typedef __attribute__((address_space(3))) void lds_void;
typedef const __attribute__((address_space(1))) void gbl_void;

__device__ __forceinline__ void gl_lds16(const bf16* g, bf16* l) {
  __builtin_amdgcn_global_load_lds((gbl_void*)g, (lds_void*)l, 16, 0, 0);
}

// ---------------- cast fp32 -> bf16 ----------------
__global__ __launch_bounds__(256) void k_cast(const float* __restrict__ x,
                                              bf16* __restrict__ o, int n) {
  int i = (blockIdx.x * 256 + threadIdx.x) * 4;
  if (i >= n) return;
  float4 v = *(const float4*)(x + i);
  bf16x4 w;
  w[0] = (bf16)v.x; w[1] = (bf16)v.y; w[2] = (bf16)v.z; w[3] = (bf16)v.w;
  *(bf16x4*)(o + i) = w;
}

// ---------------- transpose+cast: W[K][N] fp32 -> Wt[N][K] bf16 ----------------
__global__ __launch_bounds__(256) void k_transpose(const float* __restrict__ W,
                                                   bf16* __restrict__ Wt,
                                                   int K, int N) {
  __shared__ float tile[32][33];
  int nb = blockIdx.x, kb = blockIdx.y;
  int t = threadIdx.x;
  int r = t >> 3, c4 = (t & 7) * 4;
  float4 v = *(const float4*)&W[(kb * 32 + r) * N + nb * 32 + c4];
  tile[r][c4 + 0] = v.x; tile[r][c4 + 1] = v.y;
  tile[r][c4 + 2] = v.z; tile[r][c4 + 3] = v.w;
  __syncthreads();
  bf16x4 o;
  #pragma unroll
  for (int i = 0; i < 4; i++) o[i] = (bf16)tile[c4 + i][r];
  *(bf16x4*)&Wt[(nb * 32 + r) * K + kb * 32 + c4] = o;
}

// ---------------- GEMM1: qkv = x @ W_attn + b_attn ----------------
__global__ __launch_bounds__(256, 2)
void k_gemm_qkv(const bf16* __restrict__ A, const bf16* __restrict__ Bt,
                const float* __restrict__ bias,
                bf16* __restrict__ qk, bf16* __restrict__ vT) {
  __shared__ bf16 As[128 * 32];
  __shared__ bf16 Bs[128 * 32];
  const int K = 1024;
  int bn = blockIdx.x, bm = blockIdx.y;
  int t = threadIdx.x;
  int wave = t >> 6, lane = t & 63, c = lane & 15, quad = lane >> 4;
  int wm = wave & 1, wn = wave >> 1;
  int ldrow = lane >> 2, ldcol = (lane & 3) * 8;

  const bf16* Ag = A + (size_t)(bm * 128) * K;
  const bf16* Bg = Bt + (size_t)(bn * 128) * K;

  f32x4 acc[4][4] = {};

  for (int k0 = 0; k0 < K; k0 += 32) {
    __syncthreads();
    #pragma unroll
    for (int q = 0; q < 2; q++) {
      int r0 = (wave * 2 + q) * 16;
      gl_lds16(&Ag[(size_t)(r0 + ldrow) * K + k0 + ldcol], &As[r0 * 32]);
      gl_lds16(&Bg[(size_t)(r0 + ldrow) * K + k0 + ldcol], &Bs[r0 * 32]);
    }
    __syncthreads();
    bf16x8 af[4];
    #pragma unroll
    for (int mt = 0; mt < 4; mt++)
      af[mt] = *(const bf16x8*)&As[(wm * 64 + mt * 16 + c) * 32 + quad * 8];
    #pragma unroll
    for (int nt = 0; nt < 4; nt++) {
      bf16x8 bfr = *(const bf16x8*)&Bs[(wn * 64 + nt * 16 + c) * 32 + quad * 8];
      #pragma unroll
      for (int mt = 0; mt < 4; mt++)
        acc[mt][nt] = __builtin_amdgcn_mfma_f32_16x16x32_bf16(af[mt], bfr, acc[mt][nt], 0, 0, 0);
    }
  }

  #pragma unroll
  for (int nt = 0; nt < 4; nt++) {
    int n = bn * 128 + wn * 64 + nt * 16 + c;
    int which = n >> 10, nl = n & 1023;
    int h = nl >> 6, hd = nl & 63;
    float bv = bias[n];
    #pragma unroll
    for (int mt = 0; mt < 4; mt++) {
      int m0 = bm * 128 + wm * 64 + mt * 16 + quad * 4;
      int b = m0 >> 11, s0 = m0 & 2047;
      int bh = b * N_HEAD + h;
      if (which == 2) {
        bf16x4 o;
        #pragma unroll
        for (int r = 0; r < 4; r++) o[r] = (bf16)(acc[mt][nt][r] + bv);
        *(bf16x4*)&vT[((size_t)bh * HEAD_DIM + hd) * S_LEN + s0] = o;
      } else if (which == 0) {
        #pragma unroll
        for (int r = 0; r < 4; r++)
          qk[(bh * S_LEN + s0 + r) * HEAD_DIM + hd] = (bf16)((acc[mt][nt][r] + bv) * Q_SCALE);
      } else {
        #pragma unroll
        for (int r = 0; r < 4; r++)
          qk[BH * S_LEN * HEAD_DIM + (bh * S_LEN + s0 + r) * HEAD_DIM + hd] = (bf16)(acc[mt][nt][r] + bv);
      }
    }
  }
}

// ---------------- flash attention (causal), one 64-row q-tile per block ----------------
// grid 1024: bh = bx&31, tile = 31 - (bx>>5)  (descending tile order: the
// 32-iteration blocks dispatch first -> good greedy packing at 4 blocks/CU).
// LDS 40KB -> 4 blocks/CU resident (vs 2 for the old 48KB pair scheme);
// occupancy cap 8 -> 16 waves/CU. Blocks sharing bh are 32 apart in blockIdx
// (32 % 8 XCDs == 0) so each head's K/V stays in one XCD L2.
// LDS: XOR-swizzled (SW), double-buffered K/V (one barrier per iter).
__global__ __launch_bounds__(256, 4)
void k_attn(const bf16* __restrict__ qk, const bf16* __restrict__ vT,
            bf16* __restrict__ y) {
  __shared__ bf16 Ks[2][64][64];   // [buf][kpos][d]  (swizzled cols)
  __shared__ bf16 Vs[2][64][64];   // [buf][d][kpos]
  __shared__ bf16 Ps[64][64];      // [q][kpos], wave-private rows
  int bx = blockIdx.x;
  int bh = bx & 31;
  int tile = 31 - (bx >> 5);
  int t = threadIdx.x, w = t >> 6, lane = t & 63, c = lane & 15, quad = lane >> 4;
  const bf16* Qg = qk + (size_t)bh * (S_LEN * HEAD_DIM);
  const bf16* Kg = qk + (size_t)(BH + bh) * (S_LEN * HEAD_DIM);
  const bf16* Vg = vT + (size_t)bh * (HEAD_DIM * S_LEN);
  int b = bh >> 4, h = bh & 15;
  int srow = t >> 3, scol = (t & 7) * 8;
  int swcol = SW(srow, scol);      // same for srow and srow+32

  const int nkb = tile + 1;
  const int dthr = w * 16 + c;     // q-row within tile, for diagonal mask

  bf16x8 qf[2];
  f32x4 acc[4] = {};
  float mM = -1e30f, lL = 0.f;
  {
    int qr = tile * 64 + w * 16 + c;
    qf[0] = *(const bf16x8*)&Qg[qr * HEAD_DIM + quad * 8];
    qf[1] = *(const bf16x8*)&Qg[qr * HEAD_DIM + 32 + quad * 8];
  }

  // prologue: prefetch + stage kb=0 into buf 0
  bf16x8 kr0 = *(const bf16x8*)&Kg[srow * HEAD_DIM + scol];
  bf16x8 kr1 = *(const bf16x8*)&Kg[(srow + 32) * HEAD_DIM + scol];
  bf16x8 vr0 = *(const bf16x8*)&Vg[(size_t)srow * S_LEN + scol];
  bf16x8 vr1 = *(const bf16x8*)&Vg[(size_t)(srow + 32) * S_LEN + scol];
  *(bf16x8*)&Ks[0][srow][swcol] = kr0;
  *(bf16x8*)&Ks[0][srow + 32][swcol] = kr1;
  *(bf16x8*)&Vs[0][srow][swcol] = vr0;
  *(bf16x8*)&Vs[0][srow + 32][swcol] = vr1;

  for (int kb = 0; kb < nkb; kb++) {
    __syncthreads();   // buf[kb&1] visible; licenses writing buf[(kb+1)&1]
    int cur = kb & 1;
    bool haveNext = (kb + 1 < nkb);
    if (haveNext) {
      kr0 = *(const bf16x8*)&Kg[((kb + 1) * 64 + srow) * HEAD_DIM + scol];
      kr1 = *(const bf16x8*)&Kg[((kb + 1) * 64 + srow + 32) * HEAD_DIM + scol];
      vr0 = *(const bf16x8*)&Vg[(size_t)srow * S_LEN + (kb + 1) * 64 + scol];
      vr1 = *(const bf16x8*)&Vg[(size_t)(srow + 32) * S_LEN + (kb + 1) * 64 + scol];
    }

    bool dia = (kb == tile);

    // S^T = K Q^T : lane holds (kpos = kt*16+quad*4+r, q = c)
    f32x4 sc[4];
    #pragma unroll
    for (int kt = 0; kt < 4; kt++) {
      int kr = kt * 16 + c;
      bf16x8 kf0 = *(const bf16x8*)&Ks[cur][kr][SW(kr, quad * 8)];
      bf16x8 kf1 = *(const bf16x8*)&Ks[cur][kr][SW(kr, 32 + quad * 8)];
      f32x4 z = {};
      z = __builtin_amdgcn_mfma_f32_16x16x32_bf16(kf0, qf[0], z, 0, 0, 0);
      z = __builtin_amdgcn_mfma_f32_16x16x32_bf16(kf1, qf[1], z, 0, 0, 0);
      sc[kt] = z;
    }

    if (dia) {
      #pragma unroll
      for (int kt = 0; kt < 4; kt++)
        #pragma unroll
        for (int r = 0; r < 4; r++)
          if (kt * 16 + quad * 4 + r > dthr) sc[kt][r] = -1e30f;
    }

    // online softmax (lane's q-row = c); Ps rows are wave-private
    {
      float mx = sc[0][0];
      #pragma unroll
      for (int kt = 0; kt < 4; kt++)
        #pragma unroll
        for (int r = 0; r < 4; r++) mx = fmaxf(mx, sc[kt][r]);
      mx = fmaxf(mx, __shfl_xor(mx, 16));
      mx = fmaxf(mx, __shfl_xor(mx, 32));
      float mnew = fmaxf(mM, mx);
      float alpha = EXP2F(mM - mnew);
      float sum = 0.f;
      int prow = w * 16 + c;
      #pragma unroll
      for (int kt = 0; kt < 4; kt++) {
        bf16x4 pk;
        #pragma unroll
        for (int r = 0; r < 4; r++) {
          float pv = EXP2F(sc[kt][r] - mnew);
          sum += pv;
          pk[r] = (bf16)pv;
        }
        *(bf16x4*)&Ps[prow][SW(prow, kt * 16 + quad * 4)] = pk;
      }
      sum += __shfl_xor(sum, 16);
      sum += __shfl_xor(sum, 32);
      lL = lL * alpha + sum;
      mM = mnew;
      #pragma unroll
      for (int dt = 0; dt < 4; dt++)
        #pragma unroll
        for (int r = 0; r < 4; r++) acc[dt][r] *= alpha;
    }

    // O^T += V^T P^T
    {
      int prow = w * 16 + c;
      #pragma unroll
      for (int ks = 0; ks < 2; ks++) {
        bf16x8 pf = *(const bf16x8*)&Ps[prow][SW(prow, ks * 32 + quad * 8)];
        #pragma unroll
        for (int dt = 0; dt < 4; dt++) {
          int vrow = dt * 16 + c;
          bf16x8 vf = *(const bf16x8*)&Vs[cur][vrow][SW(vrow, ks * 32 + quad * 8)];
          acc[dt] = __builtin_amdgcn_mfma_f32_16x16x32_bf16(vf, pf, acc[dt], 0, 0, 0);
        }
      }
    }

    // stage next block into the other buffer (safe: all waves passed this
    // iter's barrier, so nobody still reads buf[cur^1] from iter kb-1)
    if (haveNext) {
      int nxt = cur ^ 1;
      *(bf16x8*)&Ks[nxt][srow][swcol] = kr0;
      *(bf16x8*)&Ks[nxt][srow + 32][swcol] = kr1;
      *(bf16x8*)&Vs[nxt][srow][swcol] = vr0;
      *(bf16x8*)&Vs[nxt][srow + 32][swcol] = vr1;
    }
  }

  {
    int q = tile * 64 + w * 16 + c;
    float linv = 1.0f / lL;
    #pragma unroll
    for (int dt = 0; dt < 4; dt++) {
      bf16x4 o;
      #pragma unroll
      for (int r = 0; r < 4; r++) o[r] = (bf16)(acc[dt][r] * linv);
      *(bf16x4*)&y[((size_t)(b * S_LEN + q) * N_HEAD + h) * HEAD_DIM + dt * 16 + quad * 4] = o;
    }
  }
}

// ---------------- GEMM2: out = y @ W_proj + b_proj, 128x64 tiles ----------------
__global__ __launch_bounds__(256, 2)
void k_gemm_proj(const bf16* __restrict__ A, const bf16* __restrict__ Bt,
                 const float* __restrict__ bias, float* __restrict__ out) {
  __shared__ bf16 As[128 * 32];
  __shared__ bf16 Bs[64 * 32];
  const int K = 1024;
  int bn = blockIdx.x, bm = blockIdx.y;
  int t = threadIdx.x;
  int wave = t >> 6, lane = t & 63, c = lane & 15, quad = lane >> 4;
  int wm = wave & 1, wn = wave >> 1;
  int ldrow = lane >> 2, ldcol = (lane & 3) * 8;

  const bf16* Ag = A + (size_t)(bm * 128) * K;
  const bf16* Bg = Bt + (size_t)(bn * 64) * K;

  f32x4 acc[4][2] = {};

  for (int k0 = 0; k0 < K; k0 += 32) {
    __syncthreads();
    #pragma unroll
    for (int q = 0; q < 2; q++) {
      int r0 = (wave * 2 + q) * 16;
      gl_lds16(&Ag[(size_t)(r0 + ldrow) * K + k0 + ldcol], &As[r0 * 32]);
    }
    gl_lds16(&Bg[(size_t)(wave * 16 + ldrow) * K + k0 + ldcol], &Bs[wave * 16 * 32]);
    __syncthreads();
    bf16x8 af[4];
    #pragma unroll
    for (int mt = 0; mt < 4; mt++)
      af[mt] = *(const bf16x8*)&As[(wm * 64 + mt * 16 + c) * 32 + quad * 8];
    #pragma unroll
    for (int nt = 0; nt < 2; nt++) {
      bf16x8 bfr = *(const bf16x8*)&Bs[(wn * 32 + nt * 16 + c) * 32 + quad * 8];
      #pragma unroll
      for (int mt = 0; mt < 4; mt++)
        acc[mt][nt] = __builtin_amdgcn_mfma_f32_16x16x32_bf16(af[mt], bfr, acc[mt][nt], 0, 0, 0);
    }
  }

  #pragma unroll
  for (int nt = 0; nt < 2; nt++) {
    int n = bn * 64 + wn * 32 + nt * 16 + c;
    float bv = bias[n];
    #pragma unroll
    for (int mt = 0; mt < 4; mt++) {
      #pragma unroll
      for (int r = 0; r < 4; r++) {
        int m = bm * 128 + wm * 64 + mt * 16 + quad * 4 + r;
        out[(size_t)m * D_DIM + n] = acc[mt][nt][r] + bv;
      }
    }
  }
}

extern "C" void kernel_launch(void* const* d_in, const int* in_sizes, int n_in,
                              void* d_out, int out_size, void* d_ws, size_t ws_size,
                              hipStream_t stream) {
  const float* x      = (const float*)d_in[0];
  const float* W_attn = (const float*)d_in[1];
  const float* b_attn = (const float*)d_in[2];
  const float* W_proj = (const float*)d_in[3];
  const float* b_proj = (const float*)d_in[4];
  float* out = (float*)d_out;

  bf16* x_bf = (bf16*)d_ws;
  bf16* wat  = x_bf + 4096 * 1024;
  bf16* wpt  = wat + 3072 * 1024;
  bf16* qk   = wpt + 1024 * 1024;
  bf16* vT   = qk + 8 * 1024 * 1024;
  bf16* y_bf = vT + 4 * 1024 * 1024;

  k_cast<<<4096, 256, 0, stream>>>(x, x_bf, 4096 * 1024);
  k_transpose<<<dim3(3072 / 32, 1024 / 32), 256, 0, stream>>>(W_attn, wat, 1024, 3072);
  k_transpose<<<dim3(1024 / 32, 1024 / 32), 256, 0, stream>>>(W_proj, wpt, 1024, 1024);
  k_gemm_qkv<<<dim3(24, 32), 256, 0, stream>>>(x_bf, wat, b_attn, qk, vT);
  k_attn<<<1024, 256, 0, stream>>>(qk, vT, y_bf);
  k_gemm_proj<<<dim3(16, 32), 256, 0, stream>>>(y_bf, wpt, b_proj, out);
}

// Round 2
// 184.366 us; speedup vs baseline: 1.0342x; 1.0115x over previous
//
#include <hip/hip_runtime.h>

typedef __bf16 bf16;
typedef __bf16 bf16x4 __attribute__((ext_vector_type(4)));
typedef __bf16 bf16x8 __attribute__((ext_vector_type(8)));
typedef float f32x4 __attribute__((ext_vector_type(4)));

#define S_LEN 2048
#define D_DIM 1024
#define N_HEAD 16
#define HEAD_DIM 64
#define M_TOK 4096
#define BH 32

#define EXP2F(x) __builtin_amdgcn_exp2f(x)
// 1/sqrt(64) * log2(e)
#define Q_SCALE 0.18033688f

// LDS bank swizzle: conflict-free for our b64/b128 access patterns (stride 64, no pad)
#define SW(r, c) ((c) ^ (((r) & 3) << 4))
// K-row bit permutation sigma: bit2->bit4, bit4->bit3, bit3->bit2.
// Storing K row kpos at LDS row sigma(kpos) makes the QK^T output's P matrix
// lane-local for the PV MFMA B-operand (pf[ks] = {p[2ks][0..3], p[2ks+1][0..3]}),
// eliminating the Ps LDS round-trip entirely.
#define SIG(r) (((r) & 0x23) | (((r) & 0x04) << 2) | (((r) & 0x18) >> 1))

typedef __attribute__((address_space(3))) void lds_void;
typedef const __attribute__((address_space(1))) void gbl_void;

__device__ __forceinline__ void gl_lds16(const bf16* g, bf16* l) {
  __builtin_amdgcn_global_load_lds((gbl_void*)g, (lds_void*)l, 16, 0, 0);
}

// ---------------- cast fp32 -> bf16 ----------------
__global__ __launch_bounds__(256) void k_cast(const float* __restrict__ x,
                                              bf16* __restrict__ o, int n) {
  int i = (blockIdx.x * 256 + threadIdx.x) * 4;
  if (i >= n) return;
  float4 v = *(const float4*)(x + i);
  bf16x4 w;
  w[0] = (bf16)v.x; w[1] = (bf16)v.y; w[2] = (bf16)v.z; w[3] = (bf16)v.w;
  *(bf16x4*)(o + i) = w;
}

// ---------------- transpose+cast: W[K][N] fp32 -> Wt[N][K] bf16 ----------------
__global__ __launch_bounds__(256) void k_transpose(const float* __restrict__ W,
                                                   bf16* __restrict__ Wt,
                                                   int K, int N) {
  __shared__ float tile[32][33];
  int nb = blockIdx.x, kb = blockIdx.y;
  int t = threadIdx.x;
  int r = t >> 3, c4 = (t & 7) * 4;
  float4 v = *(const float4*)&W[(kb * 32 + r) * N + nb * 32 + c4];
  tile[r][c4 + 0] = v.x; tile[r][c4 + 1] = v.y;
  tile[r][c4 + 2] = v.z; tile[r][c4 + 3] = v.w;
  __syncthreads();
  bf16x4 o;
  #pragma unroll
  for (int i = 0; i < 4; i++) o[i] = (bf16)tile[c4 + i][r];
  *(bf16x4*)&Wt[(nb * 32 + r) * K + kb * 32 + c4] = o;
}

// ---------------- GEMM1: qkv = x @ W_attn + b_attn ----------------
__global__ __launch_bounds__(256, 2)
void k_gemm_qkv(const bf16* __restrict__ A, const bf16* __restrict__ Bt,
                const float* __restrict__ bias,
                bf16* __restrict__ qk, bf16* __restrict__ vT) {
  __shared__ bf16 As[128 * 32];
  __shared__ bf16 Bs[128 * 32];
  const int K = 1024;
  int bn = blockIdx.x, bm = blockIdx.y;
  int t = threadIdx.x;
  int wave = t >> 6, lane = t & 63, c = lane & 15, quad = lane >> 4;
  int wm = wave & 1, wn = wave >> 1;
  int ldrow = lane >> 2, ldcol = (lane & 3) * 8;

  const bf16* Ag = A + (size_t)(bm * 128) * K;
  const bf16* Bg = Bt + (size_t)(bn * 128) * K;

  f32x4 acc[4][4] = {};

  for (int k0 = 0; k0 < K; k0 += 32) {
    __syncthreads();
    #pragma unroll
    for (int q = 0; q < 2; q++) {
      int r0 = (wave * 2 + q) * 16;
      gl_lds16(&Ag[(size_t)(r0 + ldrow) * K + k0 + ldcol], &As[r0 * 32]);
      gl_lds16(&Bg[(size_t)(r0 + ldrow) * K + k0 + ldcol], &Bs[r0 * 32]);
    }
    __syncthreads();
    bf16x8 af[4];
    #pragma unroll
    for (int mt = 0; mt < 4; mt++)
      af[mt] = *(const bf16x8*)&As[(wm * 64 + mt * 16 + c) * 32 + quad * 8];
    #pragma unroll
    for (int nt = 0; nt < 4; nt++) {
      bf16x8 bfr = *(const bf16x8*)&Bs[(wn * 64 + nt * 16 + c) * 32 + quad * 8];
      #pragma unroll
      for (int mt = 0; mt < 4; mt++)
        acc[mt][nt] = __builtin_amdgcn_mfma_f32_16x16x32_bf16(af[mt], bfr, acc[mt][nt], 0, 0, 0);
    }
  }

  #pragma unroll
  for (int nt = 0; nt < 4; nt++) {
    int n = bn * 128 + wn * 64 + nt * 16 + c;
    int which = n >> 10, nl = n & 1023;
    int h = nl >> 6, hd = nl & 63;
    float bv = bias[n];
    #pragma unroll
    for (int mt = 0; mt < 4; mt++) {
      int m0 = bm * 128 + wm * 64 + mt * 16 + quad * 4;
      int b = m0 >> 11, s0 = m0 & 2047;
      int bh = b * N_HEAD + h;
      if (which == 2) {
        bf16x4 o;
        #pragma unroll
        for (int r = 0; r < 4; r++) o[r] = (bf16)(acc[mt][nt][r] + bv);
        *(bf16x4*)&vT[((size_t)bh * HEAD_DIM + hd) * S_LEN + s0] = o;
      } else if (which == 0) {
        #pragma unroll
        for (int r = 0; r < 4; r++)
          qk[(bh * S_LEN + s0 + r) * HEAD_DIM + hd] = (bf16)((acc[mt][nt][r] + bv) * Q_SCALE);
      } else {
        #pragma unroll
        for (int r = 0; r < 4; r++)
          qk[BH * S_LEN * HEAD_DIM + (bh * S_LEN + s0 + r) * HEAD_DIM + hd] = (bf16)(acc[mt][nt][r] + bv);
      }
    }
  }
}

// ---------------- flash attention (causal), one 64-row q-tile per block ----------------
// grid 1024: bh = bx&31, tile = 31 - (bx>>5). LDS 32KB (K/V dbuf only; the P
// matrix never touches LDS: K rows are stored at SIG-permuted LDS rows, which
// makes QK^T's output P lane-local for the PV MFMA B-operand - pf[ks] is a
// pure in-register repack of the softmax'd scores). 5 blocks/CU LDS cap.
__global__ __launch_bounds__(256, 4)
void k_attn(const bf16* __restrict__ qk, const bf16* __restrict__ vT,
            bf16* __restrict__ y) {
  __shared__ bf16 Ks[2][64][64];   // [buf][sig(kpos)][d]  (swizzled cols)
  __shared__ bf16 Vs[2][64][64];   // [buf][d][kpos]
  int bx = blockIdx.x;
  int bh = bx & 31;
  int tile = 31 - (bx >> 5);
  int t = threadIdx.x, w = t >> 6, lane = t & 63, c = lane & 15, quad = lane >> 4;
  const bf16* Qg = qk + (size_t)bh * (S_LEN * HEAD_DIM);
  const bf16* Kg = qk + (size_t)(BH + bh) * (S_LEN * HEAD_DIM);
  const bf16* Vg = vT + (size_t)bh * (HEAD_DIM * S_LEN);
  int b = bh >> 4, h = bh & 15;
  int srow = t >> 3, scol = (t & 7) * 8;
  int swcol = SW(srow, scol);      // same for srow and srow+32
  int sigr = SIG(srow);            // sigma(srow+32) == sigr+32

  const int nkb = tile + 1;
  const int dthr = w * 16 + c;     // q-row within tile, for diagonal mask

  bf16x8 qf[2];
  f32x4 acc[4] = {};
  float mM = -1e30f, lL = 0.f;
  {
    int qr = tile * 64 + w * 16 + c;
    qf[0] = *(const bf16x8*)&Qg[qr * HEAD_DIM + quad * 8];
    qf[1] = *(const bf16x8*)&Qg[qr * HEAD_DIM + 32 + quad * 8];
  }

  // prologue: prefetch + stage kb=0 into buf 0 (K rows at SIG-permuted slots)
  bf16x8 kr0 = *(const bf16x8*)&Kg[srow * HEAD_DIM + scol];
  bf16x8 kr1 = *(const bf16x8*)&Kg[(srow + 32) * HEAD_DIM + scol];
  bf16x8 vr0 = *(const bf16x8*)&Vg[(size_t)srow * S_LEN + scol];
  bf16x8 vr1 = *(const bf16x8*)&Vg[(size_t)(srow + 32) * S_LEN + scol];
  *(bf16x8*)&Ks[0][sigr][swcol] = kr0;
  *(bf16x8*)&Ks[0][sigr + 32][swcol] = kr1;
  *(bf16x8*)&Vs[0][srow][swcol] = vr0;
  *(bf16x8*)&Vs[0][srow + 32][swcol] = vr1;

  for (int kb = 0; kb < nkb; kb++) {
    __syncthreads();   // buf[kb&1] visible; licenses writing buf[(kb+1)&1]
    int cur = kb & 1;
    bool haveNext = (kb + 1 < nkb);
    if (haveNext) {
      kr0 = *(const bf16x8*)&Kg[((kb + 1) * 64 + srow) * HEAD_DIM + scol];
      kr1 = *(const bf16x8*)&Kg[((kb + 1) * 64 + srow + 32) * HEAD_DIM + scol];
      vr0 = *(const bf16x8*)&Vg[(size_t)srow * S_LEN + (kb + 1) * 64 + scol];
      vr1 = *(const bf16x8*)&Vg[(size_t)(srow + 32) * S_LEN + (kb + 1) * 64 + scol];
    }

    bool dia = (kb == tile);

    // S^T = K Q^T over permuted rows: lane (c,quad) reg (kt,r) holds the score
    // for kpos = (kt>>1)*32 + quad*8 + (kt&1)*4 + r, q-col = c.
    f32x4 sc[4];
    #pragma unroll
    for (int kt = 0; kt < 4; kt++) {
      int kr = kt * 16 + c;
      bf16x8 kf0 = *(const bf16x8*)&Ks[cur][kr][SW(kr, quad * 8)];
      bf16x8 kf1 = *(const bf16x8*)&Ks[cur][kr][SW(kr, 32 + quad * 8)];
      f32x4 z = {};
      z = __builtin_amdgcn_mfma_f32_16x16x32_bf16(kf0, qf[0], z, 0, 0, 0);
      z = __builtin_amdgcn_mfma_f32_16x16x32_bf16(kf1, qf[1], z, 0, 0, 0);
      sc[kt] = z;
    }

    if (dia) {
      #pragma unroll
      for (int kt = 0; kt < 4; kt++) {
        int kbase = (kt >> 1) * 32 + quad * 8 + (kt & 1) * 4;
        #pragma unroll
        for (int r = 0; r < 4; r++)
          if (kbase + r > dthr) sc[kt][r] = -1e30f;
      }
    }

    // online softmax (lane's q-row = c); P stays in registers: pf[ks] packs
    // {p[2ks][0..3], p[2ks+1][0..3]} which is exactly the PV B-operand order.
    bf16x8 pf[2];
    {
      float mx = sc[0][0];
      #pragma unroll
      for (int kt = 0; kt < 4; kt++)
        #pragma unroll
        for (int r = 0; r < 4; r++) mx = fmaxf(mx, sc[kt][r]);
      mx = fmaxf(mx, __shfl_xor(mx, 16));
      mx = fmaxf(mx, __shfl_xor(mx, 32));
      float mnew = fmaxf(mM, mx);
      float alpha = EXP2F(mM - mnew);
      float sum = 0.f;
      #pragma unroll
      for (int kt = 0; kt < 4; kt++) {
        #pragma unroll
        for (int r = 0; r < 4; r++) {
          float pv = EXP2F(sc[kt][r] - mnew);
          sum += pv;
          pf[kt >> 1][(kt & 1) * 4 + r] = (bf16)pv;
        }
      }
      sum += __shfl_xor(sum, 16);
      sum += __shfl_xor(sum, 32);
      lL = lL * alpha + sum;
      mM = mnew;
      #pragma unroll
      for (int dt = 0; dt < 4; dt++)
        #pragma unroll
        for (int r = 0; r < 4; r++) acc[dt][r] *= alpha;
    }

    // O^T += V^T P^T  (pf kpos order matches Vs natural column order)
    #pragma unroll
    for (int ks = 0; ks < 2; ks++) {
      #pragma unroll
      for (int dt = 0; dt < 4; dt++) {
        int vrow = dt * 16 + c;
        bf16x8 vf = *(const bf16x8*)&Vs[cur][vrow][SW(vrow, ks * 32 + quad * 8)];
        acc[dt] = __builtin_amdgcn_mfma_f32_16x16x32_bf16(vf, pf[ks], acc[dt], 0, 0, 0);
      }
    }

    // stage next block into the other buffer (safe: all waves passed this
    // iter's barrier, so nobody still reads buf[cur^1] from iter kb-1)
    if (haveNext) {
      int nxt = cur ^ 1;
      *(bf16x8*)&Ks[nxt][sigr][swcol] = kr0;
      *(bf16x8*)&Ks[nxt][sigr + 32][swcol] = kr1;
      *(bf16x8*)&Vs[nxt][srow][swcol] = vr0;
      *(bf16x8*)&Vs[nxt][srow + 32][swcol] = vr1;
    }
  }

  {
    int q = tile * 64 + w * 16 + c;
    float linv = 1.0f / lL;
    #pragma unroll
    for (int dt = 0; dt < 4; dt++) {
      bf16x4 o;
      #pragma unroll
      for (int r = 0; r < 4; r++) o[r] = (bf16)(acc[dt][r] * linv);
      *(bf16x4*)&y[((size_t)(b * S_LEN + q) * N_HEAD + h) * HEAD_DIM + dt * 16 + quad * 4] = o;
    }
  }
}

// ---------------- GEMM2: out = y @ W_proj + b_proj, 128x64 tiles ----------------
__global__ __launch_bounds__(256, 2)
void k_gemm_proj(const bf16* __restrict__ A, const bf16* __restrict__ Bt,
                 const float* __restrict__ bias, float* __restrict__ out) {
  __shared__ bf16 As[128 * 32];
  __shared__ bf16 Bs[64 * 32];
  const int K = 1024;
  int bn = blockIdx.x, bm = blockIdx.y;
  int t = threadIdx.x;
  int wave = t >> 6, lane = t & 63, c = lane & 15, quad = lane >> 4;
  int wm = wave & 1, wn = wave >> 1;
  int ldrow = lane >> 2, ldcol = (lane & 3) * 8;

  const bf16* Ag = A + (size_t)(bm * 128) * K;
  const bf16* Bg = Bt + (size_t)(bn * 64) * K;

  f32x4 acc[4][2] = {};

  for (int k0 = 0; k0 < K; k0 += 32) {
    __syncthreads();
    #pragma unroll
    for (int q = 0; q < 2; q++) {
      int r0 = (wave * 2 + q) * 16;
      gl_lds16(&Ag[(size_t)(r0 + ldrow) * K + k0 + ldcol], &As[r0 * 32]);
    }
    gl_lds16(&Bg[(size_t)(wave * 16 + ldrow) * K + k0 + ldcol], &Bs[wave * 16 * 32]);
    __syncthreads();
    bf16x8 af[4];
    #pragma unroll
    for (int mt = 0; mt < 4; mt++)
      af[mt] = *(const bf16x8*)&As[(wm * 64 + mt * 16 + c) * 32 + quad * 8];
    #pragma unroll
    for (int nt = 0; nt < 2; nt++) {
      bf16x8 bfr = *(const bf16x8*)&Bs[(wn * 32 + nt * 16 + c) * 32 + quad * 8];
      #pragma unroll
      for (int mt = 0; mt < 4; mt++)
        acc[mt][nt] = __builtin_amdgcn_mfma_f32_16x16x32_bf16(af[mt], bfr, acc[mt][nt], 0, 0, 0);
    }
  }

  #pragma unroll
  for (int nt = 0; nt < 2; nt++) {
    int n = bn * 64 + wn * 32 + nt * 16 + c;
    float bv = bias[n];
    #pragma unroll
    for (int mt = 0; mt < 4; mt++) {
      #pragma unroll
      for (int r = 0; r < 4; r++) {
        int m = bm * 128 + wm * 64 + mt * 16 + quad * 4 + r;
        out[(size_t)m * D_DIM + n] = acc[mt][nt][r] + bv;
      }
    }
  }
}

extern "C" void kernel_launch(void* const* d_in, const int* in_sizes, int n_in,
                              void* d_out, int out_size, void* d_ws, size_t ws_size,
                              hipStream_t stream) {
  const float* x      = (const float*)d_in[0];
  const float* W_attn = (const float*)d_in[1];
  const float* b_attn = (const float*)d_in[2];
  const float* W_proj = (const float*)d_in[3];
  const float* b_proj = (const float*)d_in[4];
  float* out = (float*)d_out;

  bf16* x_bf = (bf16*)d_ws;
  bf16* wat  = x_bf + 4096 * 1024;
  bf16* wpt  = wat + 3072 * 1024;
  bf16* qk   = wpt + 1024 * 1024;
  bf16* vT   = qk + 8 * 1024 * 1024;
  bf16* y_bf = vT + 4 * 1024 * 1024;

  k_cast<<<4096, 256, 0, stream>>>(x, x_bf, 4096 * 1024);
  k_transpose<<<dim3(3072 / 32, 1024 / 32), 256, 0, stream>>>(W_attn, wat, 1024, 3072);
  k_transpose<<<dim3(1024 / 32, 1024 / 32), 256, 0, stream>>>(W_proj, wpt, 1024, 1024);
  k_gemm_qkv<<<dim3(24, 32), 256, 0, stream>>>(x_bf, wat, b_attn, qk, vT);
  k_attn<<<1024, 256, 0, stream>>>(qk, vT, y_bf);
  k_gemm_proj<<<dim3(16, 32), 256, 0, stream>>>(y_bf, wpt, b_proj, out);
}

// Round 3
// 181.699 us; speedup vs baseline: 1.0494x; 1.0147x over previous
//
#include <hip/hip_runtime.h>

typedef __bf16 bf16;
typedef __bf16 bf16x4 __attribute__((ext_vector_type(4)));
typedef __bf16 bf16x8 __attribute__((ext_vector_type(8)));
typedef float f32x4 __attribute__((ext_vector_type(4)));

#define S_LEN 2048
#define D_DIM 1024
#define N_HEAD 16
#define HEAD_DIM 64
#define M_TOK 4096
#define BH 32

#define EXP2F(x) __builtin_amdgcn_exp2f(x)
// 1/sqrt(64) * log2(e)
#define Q_SCALE 0.18033688f

// LDS bank swizzle: conflict-free for our b64/b128 access patterns (stride 64, no pad)
#define SW(r, c) ((c) ^ (((r) & 3) << 4))
// K-row bit permutation sigma: bit2->bit4, bit4->bit3, bit3->bit2.
// Storing K row kpos at LDS row sigma(kpos) makes the QK^T output's P matrix
// lane-local for the PV MFMA B-operand (pf[ks] = {p[2ks][0..3], p[2ks+1][0..3]}),
// eliminating the Ps LDS round-trip entirely. Note sigma preserves (r&3), so
// SW(sigma(r),c) == SW(r,c).
#define SIG(r) (((r) & 0x23) | (((r) & 0x04) << 2) | (((r) & 0x18) >> 1))

typedef __attribute__((address_space(3))) void lds_void;
typedef const __attribute__((address_space(1))) void gbl_void;

__device__ __forceinline__ void gl_lds16(const bf16* g, bf16* l) {
  __builtin_amdgcn_global_load_lds((gbl_void*)g, (lds_void*)l, 16, 0, 0);
}

// ---------------- cast fp32 -> bf16 ----------------
__global__ __launch_bounds__(256) void k_cast(const float* __restrict__ x,
                                              bf16* __restrict__ o, int n) {
  int i = (blockIdx.x * 256 + threadIdx.x) * 4;
  if (i >= n) return;
  float4 v = *(const float4*)(x + i);
  bf16x4 w;
  w[0] = (bf16)v.x; w[1] = (bf16)v.y; w[2] = (bf16)v.z; w[3] = (bf16)v.w;
  *(bf16x4*)(o + i) = w;
}

// ---------------- transpose+cast: W[K][N] fp32 -> Wt[N][K] bf16 ----------------
__global__ __launch_bounds__(256) void k_transpose(const float* __restrict__ W,
                                                   bf16* __restrict__ Wt,
                                                   int K, int N) {
  __shared__ float tile[32][33];
  int nb = blockIdx.x, kb = blockIdx.y;
  int t = threadIdx.x;
  int r = t >> 3, c4 = (t & 7) * 4;
  float4 v = *(const float4*)&W[(kb * 32 + r) * N + nb * 32 + c4];
  tile[r][c4 + 0] = v.x; tile[r][c4 + 1] = v.y;
  tile[r][c4 + 2] = v.z; tile[r][c4 + 3] = v.w;
  __syncthreads();
  bf16x4 o;
  #pragma unroll
  for (int i = 0; i < 4; i++) o[i] = (bf16)tile[c4 + i][r];
  *(bf16x4*)&Wt[(nb * 32 + r) * K + kb * 32 + c4] = o;
}

// ---------------- GEMM1: qkv = x @ W_attn + b_attn ----------------
__global__ __launch_bounds__(256, 2)
void k_gemm_qkv(const bf16* __restrict__ A, const bf16* __restrict__ Bt,
                const float* __restrict__ bias,
                bf16* __restrict__ qk, bf16* __restrict__ vT) {
  __shared__ bf16 As[128 * 32];
  __shared__ bf16 Bs[128 * 32];
  const int K = 1024;
  int bn = blockIdx.x, bm = blockIdx.y;
  int t = threadIdx.x;
  int wave = t >> 6, lane = t & 63, c = lane & 15, quad = lane >> 4;
  int wm = wave & 1, wn = wave >> 1;
  int ldrow = lane >> 2, ldcol = (lane & 3) * 8;

  const bf16* Ag = A + (size_t)(bm * 128) * K;
  const bf16* Bg = Bt + (size_t)(bn * 128) * K;

  f32x4 acc[4][4] = {};

  for (int k0 = 0; k0 < K; k0 += 32) {
    __syncthreads();
    #pragma unroll
    for (int q = 0; q < 2; q++) {
      int r0 = (wave * 2 + q) * 16;
      gl_lds16(&Ag[(size_t)(r0 + ldrow) * K + k0 + ldcol], &As[r0 * 32]);
      gl_lds16(&Bg[(size_t)(r0 + ldrow) * K + k0 + ldcol], &Bs[r0 * 32]);
    }
    __syncthreads();
    bf16x8 af[4];
    #pragma unroll
    for (int mt = 0; mt < 4; mt++)
      af[mt] = *(const bf16x8*)&As[(wm * 64 + mt * 16 + c) * 32 + quad * 8];
    #pragma unroll
    for (int nt = 0; nt < 4; nt++) {
      bf16x8 bfr = *(const bf16x8*)&Bs[(wn * 64 + nt * 16 + c) * 32 + quad * 8];
      #pragma unroll
      for (int mt = 0; mt < 4; mt++)
        acc[mt][nt] = __builtin_amdgcn_mfma_f32_16x16x32_bf16(af[mt], bfr, acc[mt][nt], 0, 0, 0);
    }
  }

  #pragma unroll
  for (int nt = 0; nt < 4; nt++) {
    int n = bn * 128 + wn * 64 + nt * 16 + c;
    int which = n >> 10, nl = n & 1023;
    int h = nl >> 6, hd = nl & 63;
    float bv = bias[n];
    #pragma unroll
    for (int mt = 0; mt < 4; mt++) {
      int m0 = bm * 128 + wm * 64 + mt * 16 + quad * 4;
      int b = m0 >> 11, s0 = m0 & 2047;
      int bh = b * N_HEAD + h;
      if (which == 2) {
        bf16x4 o;
        #pragma unroll
        for (int r = 0; r < 4; r++) o[r] = (bf16)(acc[mt][nt][r] + bv);
        *(bf16x4*)&vT[((size_t)bh * HEAD_DIM + hd) * S_LEN + s0] = o;
      } else if (which == 0) {
        #pragma unroll
        for (int r = 0; r < 4; r++)
          qk[(bh * S_LEN + s0 + r) * HEAD_DIM + hd] = (bf16)((acc[mt][nt][r] + bv) * Q_SCALE);
      } else {
        #pragma unroll
        for (int r = 0; r < 4; r++)
          qk[BH * S_LEN * HEAD_DIM + (bh * S_LEN + s0 + r) * HEAD_DIM + hd] = (bf16)(acc[mt][nt][r] + bv);
      }
    }
  }
}

// ---------------- flash attention (causal), paired q-tiles, 512 threads ----------------
// grid 512: bh = bx&31, p = bx>>5 (0..15). One block = 8 waves: waves 0-3 own
// q-tile p (16 q-rows each), waves 4-7 own q-tile 31-p. Both strips share ONE
// staged K/V double-buffer (32KB LDS) over kb = 0..31-p; strip-0 waves go idle
// (barrier-only) once kb > p. Work per block is uniform (33 active wave-iter
// units), all 512 blocks co-resident (2/CU, 16 waves/CU) -> no tail.
// P stays in registers via the SIG row permutation of K.
__global__ __launch_bounds__(512, 4)
void k_attn(const bf16* __restrict__ qk, const bf16* __restrict__ vT,
            bf16* __restrict__ y) {
  __shared__ bf16 Ks[2][64][64];   // [buf][sig(kpos)][d]  (swizzled cols)
  __shared__ bf16 Vs[2][64][64];   // [buf][d][kpos]
  int bx = blockIdx.x;
  int bh = bx & 31;
  int p = bx >> 5;                 // 0..15
  int t = threadIdx.x, w = t >> 6, lane = t & 63, c = lane & 15, quad = lane >> 4;
  int strip = w >> 2, wr = w & 3;
  int myTile = strip ? (31 - p) : p;
  const bf16* Qg = qk + (size_t)bh * (S_LEN * HEAD_DIM);
  const bf16* Kg = qk + (size_t)(BH + bh) * (S_LEN * HEAD_DIM);
  const bf16* Vg = vT + (size_t)bh * (HEAD_DIM * S_LEN);
  int b = bh >> 4, h = bh & 15;
  int srow = t >> 3, scol = (t & 7) * 8;   // 512 thr = 64 rows x 8 x 16B: one K + one V op each
  int swcol = SW(srow, scol);
  int sigr = SIG(srow);

  const int nkb = 32 - p;          // loop length (strip 1 runs all of it)
  const int myLast = strip ? (31 - p) : p;   // diagonal kb for this strip
  const int dthr = wr * 16 + c;    // q-row within tile, for diagonal mask

  bf16x8 qf[2];
  f32x4 acc[4] = {};
  float mM = -1e30f, lL = 0.f;
  {
    int qr = myTile * 64 + wr * 16 + c;
    qf[0] = *(const bf16x8*)&Qg[qr * HEAD_DIM + quad * 8];
    qf[1] = *(const bf16x8*)&Qg[qr * HEAD_DIM + 32 + quad * 8];
  }

  // prologue: prefetch + stage kb=0 into buf 0 (K rows at SIG-permuted slots)
  bf16x8 kr = *(const bf16x8*)&Kg[srow * HEAD_DIM + scol];
  bf16x8 vr = *(const bf16x8*)&Vg[(size_t)srow * S_LEN + scol];
  *(bf16x8*)&Ks[0][sigr][swcol] = kr;
  *(bf16x8*)&Vs[0][srow][swcol] = vr;

  for (int kb = 0; kb < nkb; kb++) {
    __syncthreads();   // buf[kb&1] visible; licenses writing buf[(kb+1)&1]
    int cur = kb & 1;
    bool haveNext = (kb + 1 < nkb);
    if (haveNext) {
      kr = *(const bf16x8*)&Kg[((kb + 1) * 64 + srow) * HEAD_DIM + scol];
      vr = *(const bf16x8*)&Vg[(size_t)srow * S_LEN + (kb + 1) * 64 + scol];
    }

    bool act = (kb <= myLast);     // wave-uniform
    if (act) {
      bool dia = (kb == myLast);

      // S^T = K Q^T over permuted rows: lane (c,quad) reg (kt,r) holds the
      // score for kpos = (kt>>1)*32 + quad*8 + (kt&1)*4 + r, q-col = c.
      f32x4 sc[4];
      __builtin_amdgcn_s_setprio(1);
      #pragma unroll
      for (int kt = 0; kt < 4; kt++) {
        int krr = kt * 16 + c;
        bf16x8 kf0 = *(const bf16x8*)&Ks[cur][krr][SW(krr, quad * 8)];
        bf16x8 kf1 = *(const bf16x8*)&Ks[cur][krr][SW(krr, 32 + quad * 8)];
        f32x4 z = {};
        z = __builtin_amdgcn_mfma_f32_16x16x32_bf16(kf0, qf[0], z, 0, 0, 0);
        z = __builtin_amdgcn_mfma_f32_16x16x32_bf16(kf1, qf[1], z, 0, 0, 0);
        sc[kt] = z;
      }
      __builtin_amdgcn_s_setprio(0);

      if (dia) {
        #pragma unroll
        for (int kt = 0; kt < 4; kt++) {
          int kbase = (kt >> 1) * 32 + quad * 8 + (kt & 1) * 4;
          #pragma unroll
          for (int r = 0; r < 4; r++)
            if (kbase + r > dthr) sc[kt][r] = -1e30f;
        }
      }

      // online softmax (lane's q-row = c); P stays in registers: pf[ks] packs
      // {p[2ks][0..3], p[2ks+1][0..3]} = exactly the PV B-operand order.
      bf16x8 pf[2];
      {
        float mx = sc[0][0];
        #pragma unroll
        for (int kt = 0; kt < 4; kt++)
          #pragma unroll
          for (int r = 0; r < 4; r++) mx = fmaxf(mx, sc[kt][r]);
        mx = fmaxf(mx, __shfl_xor(mx, 16));
        mx = fmaxf(mx, __shfl_xor(mx, 32));
        float mnew = fmaxf(mM, mx);
        float alpha = EXP2F(mM - mnew);
        float sum = 0.f;
        #pragma unroll
        for (int kt = 0; kt < 4; kt++) {
          #pragma unroll
          for (int r = 0; r < 4; r++) {
            float pv = EXP2F(sc[kt][r] - mnew);
            sum += pv;
            pf[kt >> 1][(kt & 1) * 4 + r] = (bf16)pv;
          }
        }
        sum += __shfl_xor(sum, 16);
        sum += __shfl_xor(sum, 32);
        lL = lL * alpha + sum;
        mM = mnew;
        #pragma unroll
        for (int dt = 0; dt < 4; dt++)
          #pragma unroll
          for (int r = 0; r < 4; r++) acc[dt][r] *= alpha;
      }

      // O^T += V^T P^T  (pf kpos order matches Vs natural column order)
      __builtin_amdgcn_s_setprio(1);
      #pragma unroll
      for (int ks = 0; ks < 2; ks++) {
        #pragma unroll
        for (int dt = 0; dt < 4; dt++) {
          int vrow = dt * 16 + c;
          bf16x8 vf = *(const bf16x8*)&Vs[cur][vrow][SW(vrow, ks * 32 + quad * 8)];
          acc[dt] = __builtin_amdgcn_mfma_f32_16x16x32_bf16(vf, pf[ks], acc[dt], 0, 0, 0);
        }
      }
      __builtin_amdgcn_s_setprio(0);
    }

    // stage next block into the other buffer (safe: different buffer than
    // buf[cur]; visibility guaranteed by next iteration's barrier)
    if (haveNext) {
      int nxt = cur ^ 1;
      *(bf16x8*)&Ks[nxt][sigr][swcol] = kr;
      *(bf16x8*)&Vs[nxt][srow][swcol] = vr;
    }
  }

  {
    int q = myTile * 64 + wr * 16 + c;
    float linv = 1.0f / lL;
    #pragma unroll
    for (int dt = 0; dt < 4; dt++) {
      bf16x4 o;
      #pragma unroll
      for (int r = 0; r < 4; r++) o[r] = (bf16)(acc[dt][r] * linv);
      *(bf16x4*)&y[((size_t)(b * S_LEN + q) * N_HEAD + h) * HEAD_DIM + dt * 16 + quad * 4] = o;
    }
  }
}

// ---------------- GEMM2: out = y @ W_proj + b_proj, 128x64 tiles ----------------
__global__ __launch_bounds__(256, 2)
void k_gemm_proj(const bf16* __restrict__ A, const bf16* __restrict__ Bt,
                 const float* __restrict__ bias, float* __restrict__ out) {
  __shared__ bf16 As[128 * 32];
  __shared__ bf16 Bs[64 * 32];
  const int K = 1024;
  int bn = blockIdx.x, bm = blockIdx.y;
  int t = threadIdx.x;
  int wave = t >> 6, lane = t & 63, c = lane & 15, quad = lane >> 4;
  int wm = wave & 1, wn = wave >> 1;
  int ldrow = lane >> 2, ldcol = (lane & 3) * 8;

  const bf16* Ag = A + (size_t)(bm * 128) * K;
  const bf16* Bg = Bt + (size_t)(bn * 64) * K;

  f32x4 acc[4][2] = {};

  for (int k0 = 0; k0 < K; k0 += 32) {
    __syncthreads();
    #pragma unroll
    for (int q = 0; q < 2; q++) {
      int r0 = (wave * 2 + q) * 16;
      gl_lds16(&Ag[(size_t)(r0 + ldrow) * K + k0 + ldcol], &As[r0 * 32]);
    }
    gl_lds16(&Bg[(size_t)(wave * 16 + ldrow) * K + k0 + ldcol], &Bs[wave * 16 * 32]);
    __syncthreads();
    bf16x8 af[4];
    #pragma unroll
    for (int mt = 0; mt < 4; mt++)
      af[mt] = *(const bf16x8*)&As[(wm * 64 + mt * 16 + c) * 32 + quad * 8];
    #pragma unroll
    for (int nt = 0; nt < 2; nt++) {
      bf16x8 bfr = *(const bf16x8*)&Bs[(wn * 32 + nt * 16 + c) * 32 + quad * 8];
      #pragma unroll
      for (int mt = 0; mt < 4; mt++)
        acc[mt][nt] = __builtin_amdgcn_mfma_f32_16x16x32_bf16(af[mt], bfr, acc[mt][nt], 0, 0, 0);
    }
  }

  #pragma unroll
  for (int nt = 0; nt < 2; nt++) {
    int n = bn * 64 + wn * 32 + nt * 16 + c;
    float bv = bias[n];
    #pragma unroll
    for (int mt = 0; mt < 4; mt++) {
      #pragma unroll
      for (int r = 0; r < 4; r++) {
        int m = bm * 128 + wm * 64 + mt * 16 + quad * 4 + r;
        out[(size_t)m * D_DIM + n] = acc[mt][nt][r] + bv;
      }
    }
  }
}

extern "C" void kernel_launch(void* const* d_in, const int* in_sizes, int n_in,
                              void* d_out, int out_size, void* d_ws, size_t ws_size,
                              hipStream_t stream) {
  const float* x      = (const float*)d_in[0];
  const float* W_attn = (const float*)d_in[1];
  const float* b_attn = (const float*)d_in[2];
  const float* W_proj = (const float*)d_in[3];
  const float* b_proj = (const float*)d_in[4];
  float* out = (float*)d_out;

  bf16* x_bf = (bf16*)d_ws;
  bf16* wat  = x_bf + 4096 * 1024;
  bf16* wpt  = wat + 3072 * 1024;
  bf16* qk   = wpt + 1024 * 1024;
  bf16* vT   = qk + 8 * 1024 * 1024;
  bf16* y_bf = vT + 4 * 1024 * 1024;

  k_cast<<<4096, 256, 0, stream>>>(x, x_bf, 4096 * 1024);
  k_transpose<<<dim3(3072 / 32, 1024 / 32), 256, 0, stream>>>(W_attn, wat, 1024, 3072);
  k_transpose<<<dim3(1024 / 32, 1024 / 32), 256, 0, stream>>>(W_proj, wpt, 1024, 1024);
  k_gemm_qkv<<<dim3(24, 32), 256, 0, stream>>>(x_bf, wat, b_attn, qk, vT);
  k_attn<<<512, 512, 0, stream>>>(qk, vT, y_bf);
  k_gemm_proj<<<dim3(16, 32), 256, 0, stream>>>(y_bf, wpt, b_proj, out);
}